// Round 1
// baseline (264.245 us; speedup 1.0000x reference)
//
#include <hip/hip_runtime.h>

// Problem constants (fixed by setup_inputs: B=4, S=2048, DIN=DOUT=4096)
constexpr int K0   = 16;
constexpr int DIN  = 4096;
constexpr int DOUT = 4096;

constexpr int BLOCK           = 256;
constexpr int COLS_PER_THREAD = 4;                         // float4 store
constexpr int COLS_PER_BLOCK  = BLOCK * COLS_PER_THREAD;   // 1024
constexpr int ROWS_PER_BLOCK  = 32;

// Kernel 1: c = sum_{t=K0}^{DOUT-1} W[0,t] * x2[0,t]   (single block)
__global__ __launch_bounds__(256) void c_reduce(const float* __restrict__ x,
                                                const float* __restrict__ W,
                                                float* __restrict__ c_out) {
    __shared__ float lds[4];
    const int tid = threadIdx.x;
    float acc = 0.0f;
    for (int t = K0 + tid; t < DOUT; t += 256)
        acc = fmaf(W[t], x[t], acc);
    // wave-64 shuffle reduction
    #pragma unroll
    for (int off = 32; off > 0; off >>= 1)
        acc += __shfl_down(acc, off, 64);
    if ((tid & 63) == 0) lds[tid >> 6] = acc;
    __syncthreads();
    if (tid == 0)
        *c_out = lds[0] + lds[1] + lds[2] + lds[3];
}

// Kernel 2: out[i,j] = dot16(x2[i,0:16], W[j,0:16]) + c
// Each thread owns 4 consecutive columns (wk in 64 VGPRs), loops over 32 rows.
// passed == (tstat < TAU) is provably always False (tstat >= 0 > TAU), so the
// reference's where/active path reduces to y1 + c exactly.
__global__ __launch_bounds__(BLOCK) void et_row(const float* __restrict__ x,
                                                const float* __restrict__ W,
                                                const float* __restrict__ c_ptr,
                                                float* __restrict__ out) {
    const int tid  = threadIdx.x;
    const int j0   = blockIdx.x * COLS_PER_BLOCK + tid * COLS_PER_THREAD;
    const int row0 = blockIdx.y * ROWS_PER_BLOCK;

    // Load wk for this thread's 4 columns: W[j][0:16], 16B-aligned float4 loads.
    float wk[COLS_PER_THREAD][K0];
    #pragma unroll
    for (int cc = 0; cc < COLS_PER_THREAD; ++cc) {
        const float4* wp = (const float4*)(W + (size_t)(j0 + cc) * DIN);
        #pragma unroll
        for (int q = 0; q < K0 / 4; ++q) {
            float4 v = wp[q];
            wk[cc][4 * q + 0] = v.x;
            wk[cc][4 * q + 1] = v.y;
            wk[cc][4 * q + 2] = v.z;
            wk[cc][4 * q + 3] = v.w;
        }
    }

    const float c = *c_ptr;

    for (int r = 0; r < ROWS_PER_BLOCK; ++r) {
        const int row = row0 + r;
        const float* xr = x + (size_t)row * DIN;

        // 16 shared xk values — whole wave reads the same 64B line (L1 broadcast).
        float xk[K0];
        #pragma unroll
        for (int q = 0; q < K0 / 4; ++q) {
            float4 v = ((const float4*)xr)[q];
            xk[4 * q + 0] = v.x;
            xk[4 * q + 1] = v.y;
            xk[4 * q + 2] = v.z;
            xk[4 * q + 3] = v.w;
        }

        float acc[COLS_PER_THREAD];
        #pragma unroll
        for (int cc = 0; cc < COLS_PER_THREAD; ++cc) {
            float s = c;
            #pragma unroll
            for (int k = 0; k < K0; ++k)
                s = fmaf(xk[k], wk[cc][k], s);
            acc[cc] = s;
        }

        float4 o = make_float4(acc[0], acc[1], acc[2], acc[3]);
        *((float4*)(out + (size_t)row * DOUT + j0)) = o;  // 1KB/wave coalesced
    }
}

extern "C" void kernel_launch(void* const* d_in, const int* in_sizes, int n_in,
                              void* d_out, int out_size, void* d_ws, size_t ws_size,
                              hipStream_t stream) {
    const float* x  = (const float*)d_in[0];   // (8192, 4096) flattened
    const float* W  = (const float*)d_in[1];   // (4096, 4096)
    float* out      = (float*)d_out;           // (8192, 4096)
    float* c_ws     = (float*)d_ws;            // scalar c

    const int nrows = in_sizes[0] / DIN;       // 8192

    c_reduce<<<1, 256, 0, stream>>>(x, W, c_ws);

    dim3 grid(DOUT / COLS_PER_BLOCK, nrows / ROWS_PER_BLOCK);  // (4, 256)
    et_row<<<grid, BLOCK, 0, stream>>>(x, W, c_ws, out);
}

// Round 2
// 244.321 us; speedup vs baseline: 1.0815x; 1.0815x over previous
//
#include <hip/hip_runtime.h>

// Problem constants (fixed by setup_inputs: B=4, S=2048, DIN=DOUT=4096)
constexpr int K0   = 16;
constexpr int DIN  = 4096;
constexpr int DOUT = 4096;

constexpr int BLOCK           = 256;
constexpr int COLS_PER_THREAD = 4;                         // float4 store
constexpr int COLS_PER_BLOCK  = BLOCK * COLS_PER_THREAD;   // 1024
constexpr int ROWS_PER_BLOCK  = 32;

typedef float vfloat4 __attribute__((ext_vector_type(4)));

// Math note: tstat = |y1|/sqrt(s2/16) >= 0 (NaN-compares-False included), and
// TAU < 0, so `passed` is identically False. The reference collapses EXACTLY to
//   out[i,j] = dot16(x2[i,0:16], W[j,0:16]) + c,
//   c = sum_{t=16}^{4095} W[0,t]*x2[0,t].
//
// Single fused kernel: each block redundantly computes c (32KB of reads,
// L2/L3-resident after first touch) — removes the 1-block c_reduce dispatch
// and its in-graph serialization with the main kernel.
__global__ __launch_bounds__(BLOCK) void et_fused(const float* __restrict__ x,
                                                  const float* __restrict__ W,
                                                  float* __restrict__ out) {
    __shared__ float lds_c[4];
    __shared__ float c_sh;
    const int tid  = threadIdx.x;
    const int j0   = blockIdx.x * COLS_PER_BLOCK + tid * COLS_PER_THREAD;
    const int row0 = blockIdx.y * ROWS_PER_BLOCK;

    // Issue wk loads first (independent long-latency) so they overlap the c loop.
    float wk[COLS_PER_THREAD][K0];
    #pragma unroll
    for (int cc = 0; cc < COLS_PER_THREAD; ++cc) {
        const float4* wp = (const float4*)(W + (size_t)(j0 + cc) * DIN);
        #pragma unroll
        for (int q = 0; q < K0 / 4; ++q) {
            float4 v = wp[q];
            wk[cc][4 * q + 0] = v.x;
            wk[cc][4 * q + 1] = v.y;
            wk[cc][4 * q + 2] = v.z;
            wk[cc][4 * q + 3] = v.w;
        }
    }

    // Per-block redundant c: coalesced strided loads over row 0 of x and W.
    float acc = 0.0f;
    for (int t = K0 + tid; t < DIN; t += BLOCK)
        acc = fmaf(W[t], x[t], acc);
    #pragma unroll
    for (int off = 32; off > 0; off >>= 1)
        acc += __shfl_down(acc, off, 64);
    if ((tid & 63) == 0) lds_c[tid >> 6] = acc;
    __syncthreads();
    if (tid == 0) c_sh = lds_c[0] + lds_c[1] + lds_c[2] + lds_c[3];
    __syncthreads();
    const float c = c_sh;

    // Row loop, unrolled x2 so two rows' xk loads are in flight together.
    #pragma unroll 2
    for (int r = 0; r < ROWS_PER_BLOCK; ++r) {
        const int row = row0 + r;
        const float* xr = x + (size_t)row * DIN;

        // 16 wave-shared xk floats — one 64B line per wave, L1 broadcast.
        float xk[K0];
        #pragma unroll
        for (int q = 0; q < K0 / 4; ++q) {
            float4 v = ((const float4*)xr)[q];
            xk[4 * q + 0] = v.x;
            xk[4 * q + 1] = v.y;
            xk[4 * q + 2] = v.z;
            xk[4 * q + 3] = v.w;
        }

        vfloat4 o;
        #pragma unroll
        for (int cc = 0; cc < COLS_PER_THREAD; ++cc) {
            float s = c;
            #pragma unroll
            for (int k = 0; k < K0; ++k)
                s = fmaf(xk[k], wk[cc][k], s);
            o[cc] = s;
        }
        // Nontemporal: 134MB output stream should not evict x/W from L2.
        __builtin_nontemporal_store(o, (vfloat4*)(out + (size_t)row * DOUT + j0));
    }
}

extern "C" void kernel_launch(void* const* d_in, const int* in_sizes, int n_in,
                              void* d_out, int out_size, void* d_ws, size_t ws_size,
                              hipStream_t stream) {
    const float* x = (const float*)d_in[0];   // (8192, 4096) flattened
    const float* W = (const float*)d_in[1];   // (4096, 4096)
    float* out     = (float*)d_out;           // (8192, 4096)

    const int nrows = in_sizes[0] / DIN;      // 8192

    dim3 grid(DOUT / COLS_PER_BLOCK, nrows / ROWS_PER_BLOCK);  // (4, 256)
    et_fused<<<grid, BLOCK, 0, stream>>>(x, W, out);
}

// Round 3
// 232.810 us; speedup vs baseline: 1.1350x; 1.0494x over previous
//
#include <hip/hip_runtime.h>

// Problem constants (fixed by setup_inputs: B=4, S=2048, DIN=DOUT=4096)
constexpr int K0   = 16;
constexpr int DIN  = 4096;
constexpr int DOUT = 4096;

constexpr int BLOCK          = 256;
constexpr int CPT            = 4;              // cols per thread (float4 store)
constexpr int COLS_PER_BLOCK = BLOCK * CPT;    // 1024
constexpr int ROWS           = 16;             // rows per block -> grid.y = 512

typedef float vfloat4 __attribute__((ext_vector_type(4)));

// Math note: tstat = |y1|/sqrt(s2/16) >= 0 (NaN compares False too), TAU < 0,
// so `passed` is identically False and the reference collapses EXACTLY to
//   out[i,j] = dot16(x2[i,0:16], W[j,0:16]) + c,
//   c = sum_{t=16}^{4095} W[0,t]*x2[0,t].
//
// Structure: one fused kernel. Per block: (a) redundant c via float4 loop
// (4 iters) + wave reduce, (b) stage 16 rows of xk (1KB) into LDS once,
// (c) store loop is ds_read(broadcast) + FMA + coalesced float4 store —
// no global loads on the critical path => pure write-stream.
__global__ __launch_bounds__(BLOCK) void et_fused(const float* __restrict__ x,
                                                  const float* __restrict__ W,
                                                  float* __restrict__ out) {
    __shared__ float xk_sh[ROWS][K0];   // 1 KB
    __shared__ float lds_c[4];
    __shared__ float c_sh;

    const int tid  = threadIdx.x;
    const int j0   = blockIdx.x * COLS_PER_BLOCK + tid * CPT;
    const int row0 = blockIdx.y * ROWS;

    // (1) Issue xk staging load early: lanes 0..63, one float4 each.
    float4 xs;
    if (tid < ROWS * 4) {
        const int r = tid >> 2, q = tid & 3;
        xs = ((const float4*)(x + (size_t)(row0 + r) * DIN))[q];
    }

    // (2) wk for this thread's 4 columns: W[j][0:16], 64B per column.
    float wk[CPT][K0];
    #pragma unroll
    for (int cc = 0; cc < CPT; ++cc) {
        const float4* wp = (const float4*)(W + (size_t)(j0 + cc) * DIN);
        #pragma unroll
        for (int q = 0; q < K0 / 4; ++q) {
            float4 v = wp[q];
            wk[cc][4 * q + 0] = v.x;
            wk[cc][4 * q + 1] = v.y;
            wk[cc][4 * q + 2] = v.z;
            wk[cc][4 * q + 3] = v.w;
        }
    }

    // (3) Per-block redundant c, float4 loads: 1020 float4s / 256 threads = 4 iters.
    // x+16 and W+16 are 64B-aligned.
    {
        const float4* xc = (const float4*)(x + K0);
        const float4* wc = (const float4*)(W + K0);
        float acc = 0.0f;
        const int nq = (DIN - K0) / 4;  // 1020
        for (int t = tid; t < nq; t += BLOCK) {
            float4 a = xc[t], b = wc[t];
            acc = fmaf(a.x, b.x, acc);
            acc = fmaf(a.y, b.y, acc);
            acc = fmaf(a.z, b.z, acc);
            acc = fmaf(a.w, b.w, acc);
        }
        #pragma unroll
        for (int off = 32; off > 0; off >>= 1)
            acc += __shfl_down(acc, off, 64);
        if ((tid & 63) == 0) lds_c[tid >> 6] = acc;
    }

    // Write staged xk to LDS.
    if (tid < ROWS * 4) {
        const int r = tid >> 2, q = tid & 3;
        float* p = &xk_sh[r][4 * q];
        p[0] = xs.x; p[1] = xs.y; p[2] = xs.z; p[3] = xs.w;
    }
    __syncthreads();
    if (tid == 0) c_sh = lds_c[0] + lds_c[1] + lds_c[2] + lds_c[3];
    __syncthreads();
    const float c = c_sh;

    // (4) Store loop: LDS broadcast reads + 64 FMAs + one float4 store per row.
    #pragma unroll 4
    for (int r = 0; r < ROWS; ++r) {
        float xk[K0];
        #pragma unroll
        for (int q = 0; q < K0 / 4; ++q) {
            vfloat4 v = *((const vfloat4*)&xk_sh[r][4 * q]);  // all lanes same addr
            xk[4 * q + 0] = v[0];
            xk[4 * q + 1] = v[1];
            xk[4 * q + 2] = v[2];
            xk[4 * q + 3] = v[3];
        }

        vfloat4 o;
        #pragma unroll
        for (int cc = 0; cc < CPT; ++cc) {
            float s = c;
            #pragma unroll
            for (int k = 0; k < K0; ++k)
                s = fmaf(xk[k], wk[cc][k], s);
            o[cc] = s;
        }
        *((vfloat4*)(out + (size_t)(row0 + r) * DOUT + j0)) = o;  // 1KB/wave
    }
}

extern "C" void kernel_launch(void* const* d_in, const int* in_sizes, int n_in,
                              void* d_out, int out_size, void* d_ws, size_t ws_size,
                              hipStream_t stream) {
    const float* x = (const float*)d_in[0];   // (8192, 4096) flattened
    const float* W = (const float*)d_in[1];   // (4096, 4096)
    float* out     = (float*)d_out;           // (8192, 4096)

    const int nrows = in_sizes[0] / DIN;      // 8192

    dim3 grid(DOUT / COLS_PER_BLOCK, nrows / ROWS);  // (4, 512)
    et_fused<<<grid, BLOCK, 0, stream>>>(x, W, out);
}